// Round 1
// baseline (370.021 us; speedup 1.0000x reference)
//
#include <hip/hip_runtime.h>
#include <cmath>

#define B_N 512
#define T_N 50
#define GRIDN 13
#define A_N 9
#define P_N 1521          // 13*13*9
#define ROW 85            // 5 + 80 classes
#define NCLS 80

struct Entry {
    int prior;
    float tx, ty, tw, th;
    unsigned int cls[3];   // 80-bit class one-hot mask
};                          // 32 bytes

// ---------------------------------------------------------------------------
// Kernel 1: per-image target assignment (1 thread per image; serial so the
// last-wins duplicate-scatter semantics of jnp .at[].set() are preserved).
// ---------------------------------------------------------------------------
__global__ void build_kernel(const float* __restrict__ tgt,
                             const float* __restrict__ anchors,
                             Entry* __restrict__ entries,
                             int* __restrict__ counts,
                             int* __restrict__ has)
{
    int b = blockIdx.x * blockDim.x + threadIdx.x;
    if (b >= B_N) return;

    float aw[A_N], ah[A_N];
    #pragma unroll
    for (int a = 0; a < A_N; ++a) { aw[a] = anchors[2*a]; ah[a] = anchors[2*a+1]; }

    const float* t = tgt + (size_t)b * T_N * 6;
    Entry* e = entries + (size_t)b * T_N;
    int cnt = 0;

    for (int i = 0; i < T_N; ++i) {
        float conf = t[i*6 + 4];
        if (!(conf > 0.0f)) continue;
        float x = t[i*6 + 0], y = t[i*6 + 1];
        float w = t[i*6 + 2], h = t[i*6 + 3];

        // wh-only IoU vs anchors (target wh scaled by 1000)
        float tw_px = w * 1000.0f, th_px = h * 1000.0f;
        int best = 0; float bestv = -1.0f;
        #pragma unroll
        for (int a = 0; a < A_N; ++a) {
            float inter = fminf(aw[a], tw_px) * fminf(ah[a], th_px);
            float uni   = aw[a]*ah[a] + tw_px*th_px - inter;
            float iou   = inter / (uni + 1e-16f);
            if (iou > bestv) { bestv = iou; best = a; }   // strict > == argmax first-max
        }

        int gx = (int)floorf(x * (float)GRIDN);
        int gy = (int)floorf(y * (float)GRIDN);
        int prior = gy * (GRIDN * A_N) + gx * A_N + best;

        float txv = x * (float)GRIDN - (float)gx;
        float tyv = y * (float)GRIDN - (float)gy;
        float twv = logf(w * (float)GRIDN / aw[best] + 1e-16f);
        float thv = logf(h * (float)GRIDN / ah[best] + 1e-16f);
        int cls = (int)t[i*6 + 5];

        // dedup: same prior -> overwrite box targets (last wins), OR class bit
        int j;
        for (j = 0; j < cnt; ++j) if (e[j].prior == prior) break;
        if (j == cnt) {
            e[j].prior = prior;
            e[j].cls[0] = e[j].cls[1] = e[j].cls[2] = 0u;
            ++cnt;
        }
        e[j].tx = txv; e[j].ty = tyv; e[j].tw = twv; e[j].th = thv;
        e[j].cls[cls >> 5] |= (1u << (cls & 31));
    }
    counts[b] = cnt;
    has[b]    = (cnt > 0) ? 1 : 0;
}

// ---------------------------------------------------------------------------
// Kernel 2: dense conf-column reduction over all B*P priors.
// acc[0] += has[b] ? log(1-sigmoid(conf)) : log(sigmoid(conf))   (clamped -100)
// ---------------------------------------------------------------------------
__global__ void conf_reduce_kernel(const float* __restrict__ pred,
                                   const int* __restrict__ has,
                                   float* __restrict__ acc)
{
    int p = blockIdx.x * blockDim.x + threadIdx.x;
    int b = blockIdx.y;
    float v = 0.0f;
    if (p < P_N) {
        float x = pred[((size_t)b * P_N + p) * ROW + 4];
        float s = 1.0f / (1.0f + __expf(-x));
        if (has[b]) v = fmaxf(__logf(1.0f - s), -100.0f);
        else        v = fmaxf(__logf(s),        -100.0f);
    }
    // wave64 reduce + LDS across 4 waves
    #pragma unroll
    for (int o = 32; o > 0; o >>= 1) v += __shfl_down(v, o, 64);
    __shared__ float sm[4];
    int wid = threadIdx.x >> 6;
    if ((threadIdx.x & 63) == 0) sm[wid] = v;
    __syncthreads();
    if (threadIdx.x == 0)
        atomicAdd(&acc[0], sm[0] + sm[1] + sm[2] + sm[3]);
}

// ---------------------------------------------------------------------------
// Kernel 3: sparse correction at obj priors. One block (128 thr) per image.
//   lanes 0..79 : class BCE;  lane 80: obj logp + noobj-exclusion log1mp;
//   lane 81     : box MSE.
// ---------------------------------------------------------------------------
__global__ void corr_kernel(const float* __restrict__ pred,
                            const Entry* __restrict__ entries,
                            const int* __restrict__ counts,
                            float* __restrict__ acc)
{
    int b   = blockIdx.x;
    int cnt = counts[b];
    int tid = threadIdx.x;
    float cls = 0.0f, box = 0.0f, objlp = 0.0f, objl1 = 0.0f;

    for (int e = 0; e < cnt; ++e) {
        Entry en = entries[(size_t)b * T_N + e];
        const float* row = pred + ((size_t)b * P_N + en.prior) * ROW;
        if (tid < NCLS) {
            float x  = row[5 + tid];
            float s  = 1.0f / (1.0f + __expf(-x));
            float lp = fmaxf(__logf(s),        -100.0f);
            float l1 = fmaxf(__logf(1.0f - s), -100.0f);
            float tc = ((en.cls[tid >> 5] >> (tid & 31)) & 1u) ? 1.0f : 0.0f;
            cls += -(tc * lp + (1.0f - tc) * l1);
        } else if (tid == NCLS) {
            float x = row[4];
            float s = 1.0f / (1.0f + __expf(-x));
            objlp += fmaxf(__logf(s),        -100.0f);
            objl1 += fmaxf(__logf(1.0f - s), -100.0f);
        } else if (tid == NCLS + 1) {
            float d0 = row[0] - en.tx;
            float d1 = row[1] - en.ty;
            float d2 = row[2] - en.tw;
            float d3 = row[3] - en.th;
            box += d0*d0 + d1*d1 + d2*d2 + d3*d3;
        }
    }

    // reduce cls across the 2 waves (other lanes carry 0)
    float v = cls;
    #pragma unroll
    for (int o = 32; o > 0; o >>= 1) v += __shfl_down(v, o, 64);
    __shared__ float sm[2];
    if ((tid & 63) == 0) sm[tid >> 6] = v;
    __syncthreads();
    if (tid == 0)        atomicAdd(&acc[4], sm[0] + sm[1]);
    if (tid == NCLS)     { atomicAdd(&acc[3], objlp); atomicAdd(&acc[1], objl1); }
    if (tid == NCLS + 1) atomicAdd(&acc[2], box);
}

// ---------------------------------------------------------------------------
// Kernel 4: finalize -> 5 outputs (total, box, obj, noobj, cls)
// ---------------------------------------------------------------------------
__global__ void finalize_kernel(const float* __restrict__ acc,
                                float* __restrict__ out)
{
    const float invB = 1.0f / (float)B_N;
    float S_main  = acc[0];   // sum over all priors: log1mp (has) or logp (!has)
    float S_objl1 = acc[1];   // sum of log1mp at obj priors
    float boxs    = acc[2];
    float objlp   = acc[3];   // sum of logp at obj priors
    float clss    = acc[4];

    float box_loss   = 5.0f * boxs * invB;
    float obj_loss   = -objlp * invB;
    float noobj_loss = -100.0f * (S_main - S_objl1) * invB;
    float cls_loss   = clss * invB;

    out[0] = box_loss + obj_loss + noobj_loss + cls_loss;
    out[1] = box_loss;
    out[2] = obj_loss;
    out[3] = noobj_loss;
    out[4] = cls_loss;
}

extern "C" void kernel_launch(void* const* d_in, const int* in_sizes, int n_in,
                              void* d_out, int out_size, void* d_ws, size_t ws_size,
                              hipStream_t stream)
{
    const float* pred    = (const float*)d_in[0];  // [512,1521,85]
    const float* tgt     = (const float*)d_in[1];  // [512,50,6]
    const float* anchors = (const float*)d_in[2];  // [9,2]
    float* out = (float*)d_out;                    // 5 floats

    char* ws = (char*)d_ws;
    float* acc     = (float*)ws;                    // 5 floats (padded to 32B)
    int*   counts  = (int*)(ws + 32);               // 512 ints
    int*   has     = (int*)(ws + 32 + 2048);        // 512 ints
    Entry* entries = (Entry*)(ws + 32 + 4096);      // 512*50*32B = 800 KiB

    hipMemsetAsync(acc, 0, 32, stream);

    build_kernel<<<dim3(2), dim3(256), 0, stream>>>(tgt, anchors, entries, counts, has);

    dim3 grid((P_N + 255) / 256, B_N);
    conf_reduce_kernel<<<grid, dim3(256), 0, stream>>>(pred, has, acc);

    corr_kernel<<<dim3(B_N), dim3(128), 0, stream>>>(pred, entries, counts, acc);

    finalize_kernel<<<dim3(1), dim3(1), 0, stream>>>(acc, out);
}

// Round 2
// 119.947 us; speedup vs baseline: 3.0849x; 3.0849x over previous
//
#include <hip/hip_runtime.h>
#include <cmath>

#define B_N 512
#define T_N 50
#define GRIDN 13
#define A_N 9
#define P_N 1521          // 13*13*9
#define ROW 85            // 5 + 80 classes
#define NCLS 80

struct Entry {
    int prior;
    float tx, ty, tw, th;
    unsigned int cls[3];   // 80-bit class one-hot mask
};                          // 32 bytes

// ---------------------------------------------------------------------------
// Kernel 1: per-image target assignment. ONE WAVE per image, one LANE per
// target. Last-wins dedup (jnp .at[].set semantics) resolved in-register via
// 50 shfl broadcasts; class one-hot OR'd across same-prior lanes; winners
// compacted with ballot + prefix popcount.
// ---------------------------------------------------------------------------
__global__ void build_kernel(const float* __restrict__ tgt,
                             const float* __restrict__ anchors,
                             Entry* __restrict__ entries,
                             int* __restrict__ counts,
                             int* __restrict__ has)
{
    int lane = threadIdx.x & 63;
    int wib  = threadIdx.x >> 6;
    int b    = blockIdx.x * (blockDim.x >> 6) + wib;
    if (b >= B_N) return;

    int   prior = -1;                 // -1 == invalid
    float txv = 0.f, tyv = 0.f, twv = 0.f, thv = 0.f;
    int   cls = 0;

    if (lane < T_N) {
        const float* t = tgt + ((size_t)b * T_N + lane) * 6;
        float x = t[0], y = t[1], w = t[2], h = t[3], conf = t[4];
        if (conf > 0.0f) {
            float tw_px = w * 1000.0f, th_px = h * 1000.0f;
            int best = 0; float bestv = -1.0f;
            #pragma unroll
            for (int a = 0; a < A_N; ++a) {
                float aw = anchors[2*a], ah = anchors[2*a+1];
                float inter = fminf(aw, tw_px) * fminf(ah, th_px);
                float uni   = aw*ah + tw_px*th_px - inter;
                float iou   = inter / (uni + 1e-16f);
                if (iou > bestv) { bestv = iou; best = a; }  // strict > == first-max
            }
            int gx = (int)floorf(x * (float)GRIDN);
            int gy = (int)floorf(y * (float)GRIDN);
            prior = gy * (GRIDN * A_N) + gx * A_N + best;
            txv = x * (float)GRIDN - (float)gx;
            tyv = y * (float)GRIDN - (float)gy;
            float aw = anchors[2*best], ah = anchors[2*best+1];
            twv = logf(w * (float)GRIDN / aw + 1e-16f);
            thv = logf(h * (float)GRIDN / ah + 1e-16f);
            cls = (int)t[5];
        }
    }

    bool valid = (prior >= 0);
    unsigned int m0 = 0, m1 = 0, m2 = 0;
    bool laterdup = false;
    #pragma unroll
    for (int j = 0; j < T_N; ++j) {
        int pj = __shfl(prior, j, 64);
        int cj = __shfl(cls,   j, 64);
        if (valid && pj == prior) {            // pj>=0 implied (prior>=0)
            if (j > lane) laterdup = true;
            if (cj < 32)      m0 |= 1u << cj;
            else if (cj < 64) m1 |= 1u << (cj - 32);
            else              m2 |= 1u << (cj - 64);
        }
    }
    bool winner = valid && !laterdup;

    unsigned long long mask = __ballot(winner);
    int cnt = __popcll(mask);
    if (winner) {
        int idx = __popcll(mask & ((1ull << lane) - 1ull));
        Entry* e = entries + (size_t)b * T_N + idx;
        e->prior = prior;
        e->tx = txv; e->ty = tyv; e->tw = twv; e->th = thv;
        e->cls[0] = m0; e->cls[1] = m1; e->cls[2] = m2;
    }
    if (lane == 0) { counts[b] = cnt; has[b] = (cnt > 0) ? 1 : 0; }
}

// ---------------------------------------------------------------------------
// Kernel 2: dense conf-column reduction over all B*P priors.
// acc[0] += has[b] ? log(1-sigmoid(conf)) : log(sigmoid(conf))   (clamped -100)
// ---------------------------------------------------------------------------
__global__ void conf_reduce_kernel(const float* __restrict__ pred,
                                   const int* __restrict__ has,
                                   float* __restrict__ acc)
{
    int p = blockIdx.x * blockDim.x + threadIdx.x;
    int b = blockIdx.y;
    float v = 0.0f;
    if (p < P_N) {
        float x = pred[((size_t)b * P_N + p) * ROW + 4];
        float s = 1.0f / (1.0f + __expf(-x));
        if (has[b]) v = fmaxf(__logf(1.0f - s), -100.0f);
        else        v = fmaxf(__logf(s),        -100.0f);
    }
    #pragma unroll
    for (int o = 32; o > 0; o >>= 1) v += __shfl_down(v, o, 64);
    __shared__ float sm[4];
    int wid = threadIdx.x >> 6;
    if ((threadIdx.x & 63) == 0) sm[wid] = v;
    __syncthreads();
    if (threadIdx.x == 0)
        atomicAdd(&acc[0], sm[0] + sm[1] + sm[2] + sm[3]);
}

// ---------------------------------------------------------------------------
// Kernel 3: sparse correction at obj priors. One block (128 thr) per image.
//   lanes 0..79 : class BCE;  lane 80: obj logp + noobj-exclusion log1mp;
//   lane 81     : box MSE.
// ---------------------------------------------------------------------------
__global__ void corr_kernel(const float* __restrict__ pred,
                            const Entry* __restrict__ entries,
                            const int* __restrict__ counts,
                            float* __restrict__ acc)
{
    int b   = blockIdx.x;
    int cnt = counts[b];
    int tid = threadIdx.x;
    float cls = 0.0f, box = 0.0f, objlp = 0.0f, objl1 = 0.0f;

    for (int e = 0; e < cnt; ++e) {
        Entry en = entries[(size_t)b * T_N + e];
        const float* row = pred + ((size_t)b * P_N + en.prior) * ROW;
        if (tid < NCLS) {
            float x  = row[5 + tid];
            float s  = 1.0f / (1.0f + __expf(-x));
            float lp = fmaxf(__logf(s),        -100.0f);
            float l1 = fmaxf(__logf(1.0f - s), -100.0f);
            float tc = ((en.cls[tid >> 5] >> (tid & 31)) & 1u) ? 1.0f : 0.0f;
            cls += -(tc * lp + (1.0f - tc) * l1);
        } else if (tid == NCLS) {
            float x = row[4];
            float s = 1.0f / (1.0f + __expf(-x));
            objlp += fmaxf(__logf(s),        -100.0f);
            objl1 += fmaxf(__logf(1.0f - s), -100.0f);
        } else if (tid == NCLS + 1) {
            float d0 = row[0] - en.tx;
            float d1 = row[1] - en.ty;
            float d2 = row[2] - en.tw;
            float d3 = row[3] - en.th;
            box += d0*d0 + d1*d1 + d2*d2 + d3*d3;
        }
    }

    float v = cls;
    #pragma unroll
    for (int o = 32; o > 0; o >>= 1) v += __shfl_down(v, o, 64);
    __shared__ float sm[2];
    if ((tid & 63) == 0) sm[tid >> 6] = v;
    __syncthreads();
    if (tid == 0)        atomicAdd(&acc[4], sm[0] + sm[1]);
    if (tid == NCLS)     { atomicAdd(&acc[3], objlp); atomicAdd(&acc[1], objl1); }
    if (tid == NCLS + 1) atomicAdd(&acc[2], box);
}

// ---------------------------------------------------------------------------
// Kernel 4: finalize -> 5 outputs (total, box, obj, noobj, cls)
// ---------------------------------------------------------------------------
__global__ void finalize_kernel(const float* __restrict__ acc,
                                float* __restrict__ out)
{
    const float invB = 1.0f / (float)B_N;
    float S_main  = acc[0];
    float S_objl1 = acc[1];
    float boxs    = acc[2];
    float objlp   = acc[3];
    float clss    = acc[4];

    float box_loss   = 5.0f * boxs * invB;
    float obj_loss   = -objlp * invB;
    float noobj_loss = -100.0f * (S_main - S_objl1) * invB;
    float cls_loss   = clss * invB;

    out[0] = box_loss + obj_loss + noobj_loss + cls_loss;
    out[1] = box_loss;
    out[2] = obj_loss;
    out[3] = noobj_loss;
    out[4] = cls_loss;
}

extern "C" void kernel_launch(void* const* d_in, const int* in_sizes, int n_in,
                              void* d_out, int out_size, void* d_ws, size_t ws_size,
                              hipStream_t stream)
{
    const float* pred    = (const float*)d_in[0];  // [512,1521,85]
    const float* tgt     = (const float*)d_in[1];  // [512,50,6]
    const float* anchors = (const float*)d_in[2];  // [9,2]
    float* out = (float*)d_out;                    // 5 floats

    char* ws = (char*)d_ws;
    float* acc     = (float*)ws;                    // 5 floats (padded to 32B)
    int*   counts  = (int*)(ws + 32);               // 512 ints
    int*   has     = (int*)(ws + 32 + 2048);        // 512 ints
    Entry* entries = (Entry*)(ws + 32 + 4096);      // 512*50*32B = 800 KiB

    hipMemsetAsync(acc, 0, 32, stream);

    // one wave per image: 512 waves = 128 blocks x 256 threads
    build_kernel<<<dim3(128), dim3(256), 0, stream>>>(tgt, anchors, entries, counts, has);

    dim3 grid((P_N + 255) / 256, B_N);
    conf_reduce_kernel<<<grid, dim3(256), 0, stream>>>(pred, has, acc);

    corr_kernel<<<dim3(B_N), dim3(128), 0, stream>>>(pred, entries, counts, acc);

    finalize_kernel<<<dim3(1), dim3(1), 0, stream>>>(acc, out);
}

// Round 3
// 52.942 us; speedup vs baseline: 6.9892x; 2.2656x over previous
//
#include <hip/hip_runtime.h>
#include <cmath>

#define B_N 512
#define T_N 50
#define GRIDN 13
#define A_N 9
#define P_N 1521          // 13*13*9
#define ROW 85            // 5 + 80 classes
#define NCLS 80

struct Entry {
    int prior;
    float tx, ty, tw, th;
    unsigned int cls[3];   // 80-bit class one-hot mask
};                          // 32 bytes

// ---------------------------------------------------------------------------
// Fused per-image kernel: one block (256 thr) per image.
//   Phase A (wave 0): target assignment -> Entry list in LDS.
//   Phase B (all):    dense conf-column scan (grid-stride over P).
//   Phase C (2 half-blocks): per-obj-prior correction (cls BCE / obj / box).
//   Epilogue: block reduce, thread 0 writes per-image partial losses to ws.
// No global atomics anywhere.
// ---------------------------------------------------------------------------
__global__ void __launch_bounds__(256)
main_kernel(const float* __restrict__ pred,
            const float* __restrict__ tgt,
            const float* __restrict__ anchors,
            float* __restrict__ part)     // [B][4]: box, objlp, S-objl1, cls
{
    __shared__ Entry ents[T_N];
    __shared__ int   s_cnt;
    __shared__ float red[4][5];

    const int tid  = threadIdx.x;
    const int lane = tid & 63;
    const int b    = blockIdx.x;

    // ---------------- Phase A: build (wave 0 only) ----------------
    if (tid < 64) {
        int   prior = -1;
        float txv = 0.f, tyv = 0.f, twv = 0.f, thv = 0.f;
        int   cls = 0;

        if (lane < T_N) {
            const float* t = tgt + ((size_t)b * T_N + lane) * 6;
            float x = t[0], y = t[1], w = t[2], h = t[3], conf = t[4];
            if (conf > 0.0f) {
                float tw_px = w * 1000.0f, th_px = h * 1000.0f;
                int best = 0; float bestv = -1.0f;
                #pragma unroll
                for (int a = 0; a < A_N; ++a) {
                    float aw = anchors[2*a], ah = anchors[2*a+1];
                    float inter = fminf(aw, tw_px) * fminf(ah, th_px);
                    float uni   = aw*ah + tw_px*th_px - inter;
                    float iou   = inter / (uni + 1e-16f);
                    if (iou > bestv) { bestv = iou; best = a; }  // first-max argmax
                }
                int gx = (int)floorf(x * (float)GRIDN);
                int gy = (int)floorf(y * (float)GRIDN);
                prior = gy * (GRIDN * A_N) + gx * A_N + best;
                txv = x * (float)GRIDN - (float)gx;
                tyv = y * (float)GRIDN - (float)gy;
                float aw = anchors[2*best], ah = anchors[2*best+1];
                twv = logf(w * (float)GRIDN / aw + 1e-16f);
                thv = logf(h * (float)GRIDN / ah + 1e-16f);
                cls = (int)t[5];
            }
        }

        bool valid = (prior >= 0);
        unsigned int m0 = 0, m1 = 0, m2 = 0;
        bool laterdup = false;
        #pragma unroll
        for (int j = 0; j < T_N; ++j) {
            int pj = __shfl(prior, j, 64);
            int cj = __shfl(cls,   j, 64);
            if (valid && pj == prior) {
                if (j > lane) laterdup = true;   // last-wins .at[].set semantics
                if (cj < 32)      m0 |= 1u << cj;
                else if (cj < 64) m1 |= 1u << (cj - 32);
                else              m2 |= 1u << (cj - 64);
            }
        }
        bool winner = valid && !laterdup;
        unsigned long long mask = __ballot(winner);
        if (winner) {
            int idx = __popcll(mask & ((1ull << lane) - 1ull));
            Entry* e = &ents[idx];
            e->prior = prior;
            e->tx = txv; e->ty = tyv; e->tw = twv; e->th = thv;
            e->cls[0] = m0; e->cls[1] = m1; e->cls[2] = m2;
        }
        if (lane == 0) s_cnt = __popcll(mask);
    }
    __syncthreads();

    const int  cnt  = s_cnt;
    const bool hasv = (cnt > 0);

    // ---------------- Phase B: dense conf-column scan ----------------
    const float* pb = pred + (size_t)b * P_N * ROW;
    float s_main = 0.0f;
    #pragma unroll
    for (int p = tid; p < P_N; p += 256) {
        float x = pb[(size_t)p * ROW + 4];
        float s = 1.0f / (1.0f + __expf(-x));
        float v = hasv ? fmaxf(__logf(1.0f - s), -100.0f)
                       : fmaxf(__logf(s),        -100.0f);
        s_main += v;
    }

    // ---------------- Phase C: obj-prior corrections ----------------
    float cls_s = 0.0f, box_s = 0.0f, objlp = 0.0f, objl1 = 0.0f;
    {
        const int half = tid >> 7;      // 0 or 1
        const int lt   = tid & 127;
        for (int e = half; e < cnt; e += 2) {
            Entry en = ents[e];
            const float* row = pb + (size_t)en.prior * ROW;
            if (lt < NCLS) {
                float x  = row[5 + lt];
                float s  = 1.0f / (1.0f + __expf(-x));
                float lp = fmaxf(__logf(s),        -100.0f);
                float l1 = fmaxf(__logf(1.0f - s), -100.0f);
                float tc = ((en.cls[lt >> 5] >> (lt & 31)) & 1u) ? 1.0f : 0.0f;
                cls_s += -(tc * lp + (1.0f - tc) * l1);
            } else if (lt == NCLS) {
                float x = row[4];
                float s = 1.0f / (1.0f + __expf(-x));
                objlp += fmaxf(__logf(s),        -100.0f);
                objl1 += fmaxf(__logf(1.0f - s), -100.0f);
            } else if (lt == NCLS + 1) {
                float d0 = row[0] - en.tx;
                float d1 = row[1] - en.ty;
                float d2 = row[2] - en.tw;
                float d3 = row[3] - en.th;
                box_s += d0*d0 + d1*d1 + d2*d2 + d3*d3;
            }
        }
    }

    // ---------------- Epilogue: block reduce 5 values ----------------
    float v0 = s_main, v1 = objl1, v2 = objlp, v3 = box_s, v4 = cls_s;
    #pragma unroll
    for (int o = 32; o > 0; o >>= 1) {
        v0 += __shfl_down(v0, o, 64);
        v1 += __shfl_down(v1, o, 64);
        v2 += __shfl_down(v2, o, 64);
        v3 += __shfl_down(v3, o, 64);
        v4 += __shfl_down(v4, o, 64);
    }
    const int w = tid >> 6;
    if (lane == 0) {
        red[w][0] = v0; red[w][1] = v1; red[w][2] = v2;
        red[w][3] = v3; red[w][4] = v4;
    }
    __syncthreads();
    if (tid == 0) {
        float S  = red[0][0] + red[1][0] + red[2][0] + red[3][0];
        float L1 = red[0][1] + red[1][1] + red[2][1] + red[3][1];
        float LP = red[0][2] + red[1][2] + red[2][2] + red[3][2];
        float BX = red[0][3] + red[1][3] + red[2][3] + red[3][3];
        float CL = red[0][4] + red[1][4] + red[2][4] + red[3][4];
        float* o = part + (size_t)b * 4;
        o[0] = 5.0f * BX;              // box_i
        o[1] = -LP;                    // obj_i
        o[2] = -100.0f * (S - L1);     // noobj_i (valid for empty branch: L1==0)
        o[3] = CL;                     // cls_i
    }
}

// ---------------------------------------------------------------------------
// Finalize: reduce 512x4 partials -> 5 outputs (total, box, obj, noobj, cls)
// ---------------------------------------------------------------------------
__global__ void __launch_bounds__(256)
finalize_kernel(const float* __restrict__ part, float* __restrict__ out)
{
    __shared__ float red[4][4];
    const int tid  = threadIdx.x;
    const int lane = tid & 63;

    float a0 = 0, a1 = 0, a2 = 0, a3 = 0;
    for (int b = tid; b < B_N; b += 256) {
        const float* p = part + (size_t)b * 4;
        a0 += p[0]; a1 += p[1]; a2 += p[2]; a3 += p[3];
    }
    #pragma unroll
    for (int o = 32; o > 0; o >>= 1) {
        a0 += __shfl_down(a0, o, 64);
        a1 += __shfl_down(a1, o, 64);
        a2 += __shfl_down(a2, o, 64);
        a3 += __shfl_down(a3, o, 64);
    }
    const int w = tid >> 6;
    if (lane == 0) { red[w][0] = a0; red[w][1] = a1; red[w][2] = a2; red[w][3] = a3; }
    __syncthreads();
    if (tid == 0) {
        const float invB = 1.0f / (float)B_N;
        float box   = (red[0][0] + red[1][0] + red[2][0] + red[3][0]) * invB;
        float obj   = (red[0][1] + red[1][1] + red[2][1] + red[3][1]) * invB;
        float noobj = (red[0][2] + red[1][2] + red[2][2] + red[3][2]) * invB;
        float cls   = (red[0][3] + red[1][3] + red[2][3] + red[3][3]) * invB;
        out[0] = box + obj + noobj + cls;
        out[1] = box;
        out[2] = obj;
        out[3] = noobj;
        out[4] = cls;
    }
}

extern "C" void kernel_launch(void* const* d_in, const int* in_sizes, int n_in,
                              void* d_out, int out_size, void* d_ws, size_t ws_size,
                              hipStream_t stream)
{
    const float* pred    = (const float*)d_in[0];  // [512,1521,85]
    const float* tgt     = (const float*)d_in[1];  // [512,50,6]
    const float* anchors = (const float*)d_in[2];  // [9,2]
    float* out  = (float*)d_out;                   // 5 floats
    float* part = (float*)d_ws;                    // 512*4 floats

    main_kernel<<<dim3(B_N), dim3(256), 0, stream>>>(pred, tgt, anchors, part);
    finalize_kernel<<<dim3(1), dim3(256), 0, stream>>>(part, out);
}